// Round 1
// baseline (592.995 us; speedup 1.0000x reference)
//
#include <hip/hip_runtime.h>
#include <hip/hip_bf16.h>

#define HH 100
#define WW 352
#define NB 2
#define LL 5
#define NN 10
#define CCH 64
#define HW (HH*WW)
#define KTOP (HW/4)
#define HP (HH+6)
#define WP 390   // 6*64 + 6, covers conv reads for padded W tiles

typedef __bf16 bf16x8 __attribute__((ext_vector_type(8)));
typedef float f32x4 __attribute__((ext_vector_type(4)));

// ws layout (bytes)
#define WS_CONF 0u
#define WS_TAU  1408000u
#define WS_WTP  1408064u
#define WS_PAD  1809536u
#define PAD_BYTES ((size_t)NB*HP*WP*CCH*2)

__device__ __forceinline__ void load_theta(const float* __restrict__ ptm, int b, int l, float th[6]) {
#pragma clang fp contract(off)
  const float* tb = ptm + ((b*LL + 0)*LL + l)*16;  // pairwise_t_matrix[b,0,l,:,:]
  th[0] = tb[0] * 1.0f;
  th[1] = tb[1] * (float)(100.0/352.0);
  th[2] = tb[3] * (float)(2.0/(2.0*0.4*352.0));
  th[3] = tb[4] * (float)(352.0/100.0);
  th[4] = tb[5] * 1.0f;
  th[5] = tb[7] * (float)(2.0/(2.0*0.4*100.0));
}

// --- Kernel 1: conf_w[n,h,w] = bilinear-warp of sigmoid(max(psm[n,0],psm[n,1])) ---
__global__ void conf_warp_kernel(const float* __restrict__ psm,
                                 const float* __restrict__ ptm,
                                 float* __restrict__ conf_w) {
#pragma clang fp contract(off)
  int w = blockIdx.x * 128 + threadIdx.x;
  int h = blockIdx.y;
  int n = blockIdx.z;
  if (w >= WW) return;
  int b = n / LL, l = n % LL;
  float th[6];
  load_theta(ptm, b, l, th);
  float gy = ((float)h + 0.5f) * (float)(2.0/100.0) - 1.0f;
  float gx = ((float)w + 0.5f) * (float)(2.0/352.0) - 1.0f;
  float sx = th[0]*gx + th[1]*gy + th[2];
  float sy = th[3]*gx + th[4]*gy + th[5];
  float px = (sx + 1.0f) * ((float)WW * 0.5f) - 0.5f;
  float py = (sy + 1.0f) * ((float)HH * 0.5f) - 0.5f;
  float x0 = floorf(px), y0 = floorf(py);
  float wx1 = px - x0, wx0 = 1.0f - wx1;
  float wy1 = py - y0, wy0 = 1.0f - wy1;
  const float* p0 = psm + (size_t)(n*2 + 0)*HW;
  const float* p1 = psm + (size_t)(n*2 + 1)*HW;
  float yy[2] = {y0, y0 + 1.0f};
  float xx[2] = {x0, x0 + 1.0f};
  float wgt[2][2] = {{wy0*wx0, wy0*wx1}, {wy1*wx0, wy1*wx1}};
  float out = 0.0f;
  for (int iy = 0; iy < 2; ++iy) {
    for (int ix = 0; ix < 2; ++ix) {
      float yv = yy[iy], xv = xx[ix];
      float yc = fminf(fmaxf(yv, 0.0f), (float)(HH-1));
      float xc = fminf(fmaxf(xv, 0.0f), (float)(WW-1));
      int yi = (int)yc, xi = (int)xc;
      int idx = yi*WW + xi;
      float m = fmaxf(p0[idx], p1[idx]);
      float v = 1.0f / (1.0f + expf(-m));
      bool valid = (yv >= 0.0f) && (yv <= (float)(HH-1)) && (xv >= 0.0f) && (xv <= (float)(WW-1));
      out += (valid ? v : 0.0f) * wgt[iy][ix];
    }
  }
  conf_w[(size_t)n*HW + h*WW + w] = out;
}

// --- Kernel 2: exact K-th largest per image via 4-round MSB radix select ---
__global__ void topk_kernel(const float* __restrict__ conf_w, float* __restrict__ tau) {
  __shared__ unsigned int hist[256];
  __shared__ unsigned int s_prefix;
  __shared__ int s_k;
  int n = blockIdx.x;
  const float* src = conf_w + (size_t)n*HW;
  if (threadIdx.x == 0) { s_prefix = 0u; s_k = KTOP; }
  __syncthreads();
  for (int round = 0; round < 4; ++round) {
    int shift = 24 - round*8;
    for (int i = threadIdx.x; i < 256; i += blockDim.x) hist[i] = 0u;
    __syncthreads();
    unsigned int prefix = s_prefix;
    unsigned int maskhi = (round == 0) ? 0u : (0xFFFFFFFFu << (shift + 8));
    for (int i = threadIdx.x; i < HW; i += blockDim.x) {
      unsigned int u = __float_as_uint(src[i]);  // all values >= 0 -> bit order = float order
      if ((u & maskhi) == prefix)
        atomicAdd(&hist[(u >> shift) & 255u], 1u);
    }
    __syncthreads();
    if (threadIdx.x == 0) {
      int k = s_k;
      unsigned int running = 0u;
      for (int bb = 255; bb >= 0; --bb) {
        unsigned int c = hist[bb];
        if (running + c >= (unsigned int)k) {
          s_prefix = prefix | ((unsigned int)bb << shift);
          s_k = k - (int)running;
          break;
        }
        running += c;
      }
    }
    __syncthreads();
  }
  if (threadIdx.x == 0) tau[n] = __uint_as_float(s_prefix);
}

// --- Kernel 3: weights fuse_w[k][c][dy][dx] -> wtp[(dy*7+dx)*64 + k][c] bf16 ---
__global__ void pack_w_kernel(const float* __restrict__ fw, __bf16* __restrict__ wtp) {
  int idx = blockIdx.x*256 + threadIdx.x;
  if (idx >= CCH*CCH*49) return;
  int c = idx & 63;
  int k = (idx >> 6) & 63;
  int dydx = idx >> 12;
  wtp[((size_t)dydx*CCH + k)*CCH + c] = (__bf16)fw[((size_t)k*CCH + c)*49 + dydx];
}

// --- Kernel 4: fused warp + mask + mean over L, write bf16 NHWC into padded buffer ---
__global__ __launch_bounds__(256) void warp_avg_kernel(
    const float* __restrict__ x, const float* __restrict__ ptm,
    const float* __restrict__ conf_w, const float* __restrict__ tau,
    __bf16* __restrict__ pad) {
  int tx = threadIdx.x;     // w within tile, 0..63
  int cq = threadIdx.y;     // channel quarter, 0..3
  int w = blockIdx.x*64 + tx;
  int h = blockIdx.y;
  int b = blockIdx.z;
  if (w >= WW) return;      // halo stays zero from memset
  float acc[16];
#pragma unroll
  for (int i = 0; i < 16; ++i) acc[i] = 0.0f;
  float gy = ((float)h + 0.5f) * (float)(2.0/100.0) - 1.0f;
  float gx = ((float)w + 0.5f) * (float)(2.0/352.0) - 1.0f;
  for (int l = 0; l < LL; ++l) {
    int n = b*LL + l;
    float mk = 1.0f;
    if (l != 0)
      mk = (conf_w[(size_t)n*HW + h*WW + w] >= tau[n]) ? 1.0f : 0.0f;
    if (mk == 0.0f) continue;   // skip 4*16 loads when masked out
    float th[6];
    load_theta(ptm, b, l, th);
    float sx = th[0]*gx + th[1]*gy + th[2];
    float sy = th[3]*gx + th[4]*gy + th[5];
    float px = (sx + 1.0f) * ((float)WW*0.5f) - 0.5f;
    float py = (sy + 1.0f) * ((float)HH*0.5f) - 0.5f;
    float x0 = floorf(px), y0 = floorf(py);
    float wx1 = px - x0, wx0 = 1.0f - wx1;
    float wy1 = py - y0, wy0 = 1.0f - wy1;
    float y1 = y0 + 1.0f, x1 = x0 + 1.0f;
    bool vy0 = (y0 >= 0.0f) && (y0 <= (float)(HH-1));
    bool vy1 = (y1 >= 0.0f) && (y1 <= (float)(HH-1));
    bool vx0 = (x0 >= 0.0f) && (x0 <= (float)(WW-1));
    bool vx1 = (x1 >= 0.0f) && (x1 <= (float)(WW-1));
    int yi0 = (int)fminf(fmaxf(y0, 0.0f), (float)(HH-1));
    int yi1 = (int)fminf(fmaxf(y1, 0.0f), (float)(HH-1));
    int xi0 = (int)fminf(fmaxf(x0, 0.0f), (float)(WW-1));
    int xi1 = (int)fminf(fmaxf(x1, 0.0f), (float)(WW-1));
    float w00 = wy0*wx0 * ((vy0 && vx0) ? 1.0f : 0.0f);
    float w01 = wy0*wx1 * ((vy0 && vx1) ? 1.0f : 0.0f);
    float w10 = wy1*wx0 * ((vy1 && vx0) ? 1.0f : 0.0f);
    float w11 = wy1*wx1 * ((vy1 && vx1) ? 1.0f : 0.0f);
    int o00 = yi0*WW + xi0, o01 = yi0*WW + xi1;
    int o10 = yi1*WW + xi0, o11 = yi1*WW + xi1;
    const float* xb = x + ((size_t)n*CCH + cq*16)*HW;
#pragma unroll
    for (int c = 0; c < 16; ++c) {
      const float* xc = xb + (size_t)c*HW;
      acc[c] += xc[o00]*w00 + xc[o01]*w01 + xc[o10]*w10 + xc[o11]*w11;
    }
  }
  __bf16* dst = pad + (((size_t)b*HP + (h+3))*WP + (w+3))*CCH + cq*16;
#pragma unroll
  for (int c = 0; c < 16; ++c) dst[c] = (__bf16)(acc[c]*0.2f);
}

// --- Kernel 5: 7x7 conv as implicit GEMM, bf16 MFMA 16x16x32 ---
// A = weights (M=kout), B = input pixels (N=w run), K = cin (2 chunks of 32) x 49 taps.
__global__ __launch_bounds__(256) void conv_kernel(
    const __bf16* __restrict__ pad, const __bf16* __restrict__ wtp,
    const float* __restrict__ fb, float* __restrict__ out) {
  int tid = threadIdx.x;
  int wave = tid >> 6, lane = tid & 63;
  int quad = lane >> 4, l16 = lane & 15;
  int h = blockIdx.y, b = blockIdx.z;
  int wpix = blockIdx.x*64 + wave*16 + l16;
  f32x4 acc0 = {0.f,0.f,0.f,0.f}, acc1 = {0.f,0.f,0.f,0.f};
  f32x4 acc2 = {0.f,0.f,0.f,0.f}, acc3 = {0.f,0.f,0.f,0.f};
  const __bf16* prow = pad + (((size_t)b*HP + h)*WP + wpix)*CCH + quad*8;
#pragma unroll 1
  for (int dy = 0; dy < 7; ++dy) {
#pragma unroll 1
    for (int dx = 0; dx < 7; ++dx) {
      const __bf16* pin = prow + (dy*WP + dx)*CCH;
      const __bf16* pw  = wtp + ((size_t)(dy*7 + dx)*CCH + l16)*CCH + quad*8;
#pragma unroll
      for (int kc = 0; kc < 2; ++kc) {
        bf16x8 bf = *reinterpret_cast<const bf16x8*>(pin + kc*32);
        bf16x8 a0 = *reinterpret_cast<const bf16x8*>(pw + kc*32);
        bf16x8 a1 = *reinterpret_cast<const bf16x8*>(pw + 16*CCH + kc*32);
        bf16x8 a2 = *reinterpret_cast<const bf16x8*>(pw + 32*CCH + kc*32);
        bf16x8 a3 = *reinterpret_cast<const bf16x8*>(pw + 48*CCH + kc*32);
        acc0 = __builtin_amdgcn_mfma_f32_16x16x32_bf16(a0, bf, acc0, 0, 0, 0);
        acc1 = __builtin_amdgcn_mfma_f32_16x16x32_bf16(a1, bf, acc1, 0, 0, 0);
        acc2 = __builtin_amdgcn_mfma_f32_16x16x32_bf16(a2, bf, acc2, 0, 0, 0);
        acc3 = __builtin_amdgcn_mfma_f32_16x16x32_bf16(a3, bf, acc3, 0, 0, 0);
      }
    }
  }
  if (wpix < WW) {
    int base = (b*CCH*HH + h)*WW + wpix;
#pragma unroll
    for (int r = 0; r < 4; ++r) {
      int k0 = 0*16 + quad*4 + r;
      int k1 = 1*16 + quad*4 + r;
      int k2 = 2*16 + quad*4 + r;
      int k3 = 3*16 + quad*4 + r;
      out[base + k0*HW] = acc0[r] + fb[k0];
      out[base + k1*HW] = acc1[r] + fb[k1];
      out[base + k2*HW] = acc2[r] + fb[k2];
      out[base + k3*HW] = acc3[r] + fb[k3];
    }
  }
}

extern "C" void kernel_launch(void* const* d_in, const int* in_sizes, int n_in,
                              void* d_out, int out_size, void* d_ws, size_t ws_size,
                              hipStream_t stream) {
  (void)in_sizes; (void)n_in; (void)out_size; (void)ws_size;
  const float* x   = (const float*)d_in[0];
  const float* psm = (const float*)d_in[1];
  // d_in[2] = record_len (unused by reference)
  const float* ptm = (const float*)d_in[3];
  const float* fw  = (const float*)d_in[4];
  const float* fb  = (const float*)d_in[5];
  float* out = (float*)d_out;
  char* ws = (char*)d_ws;
  float*  conf = (float*)(ws + WS_CONF);
  float*  tau  = (float*)(ws + WS_TAU);
  __bf16* wtp  = (__bf16*)(ws + WS_WTP);
  __bf16* pad  = (__bf16*)(ws + WS_PAD);

  hipMemsetAsync(pad, 0, PAD_BYTES, stream);
  conf_warp_kernel<<<dim3(3, HH, NN), 128, 0, stream>>>(psm, ptm, conf);
  topk_kernel<<<NN, 256, 0, stream>>>(conf, tau);
  pack_w_kernel<<<(CCH*CCH*49 + 255)/256, 256, 0, stream>>>(fw, wtp);
  warp_avg_kernel<<<dim3(6, HH, NB), dim3(64, 4), 0, stream>>>(x, ptm, conf, tau, pad);
  conv_kernel<<<dim3(6, HH, NB), 256, 0, stream>>>(pad, wtp, fb, out);
}

// Round 2
// 490.497 us; speedup vs baseline: 1.2090x; 1.2090x over previous
//
#include <hip/hip_runtime.h>
#include <hip/hip_bf16.h>

#define HH 100
#define WW 352
#define NB 2
#define LL 5
#define NN 10
#define CCH 64
#define HW (HH*WW)
#define KTOP (HW/4)
#define HP (HH+6)
#define WP 390   // 6*64 + 6, covers conv reads for padded W tiles

typedef __bf16 bf16x8 __attribute__((ext_vector_type(8)));
typedef float f32x4 __attribute__((ext_vector_type(4)));

// ws layout (bytes)
#define WS_CONF 0u
#define WS_TAU  1408000u
#define WS_WTP  1408064u
#define WS_PAD  1809536u
#define PAD_BYTES ((size_t)NB*HP*WP*CCH*2)

__device__ __forceinline__ void load_theta(const float* __restrict__ ptm, int b, int l, float th[6]) {
#pragma clang fp contract(off)
  const float* tb = ptm + ((b*LL + 0)*LL + l)*16;  // pairwise_t_matrix[b,0,l,:,:]
  th[0] = tb[0] * 1.0f;
  th[1] = tb[1] * (float)(100.0/352.0);
  th[2] = tb[3] * (float)(2.0/(2.0*0.4*352.0));
  th[3] = tb[4] * (float)(352.0/100.0);
  th[4] = tb[5] * 1.0f;
  th[5] = tb[7] * (float)(2.0/(2.0*0.4*100.0));
}

// --- Kernel 1: conf_w[n,h,w] = bilinear-warp of sigmoid(max(psm[n,0],psm[n,1])) ---
__global__ void conf_warp_kernel(const float* __restrict__ psm,
                                 const float* __restrict__ ptm,
                                 float* __restrict__ conf_w) {
#pragma clang fp contract(off)
  int w = blockIdx.x * 128 + threadIdx.x;
  int h = blockIdx.y;
  int n = blockIdx.z;
  if (w >= WW) return;
  int b = n / LL, l = n % LL;
  float th[6];
  load_theta(ptm, b, l, th);
  float gy = ((float)h + 0.5f) * (float)(2.0/100.0) - 1.0f;
  float gx = ((float)w + 0.5f) * (float)(2.0/352.0) - 1.0f;
  float sx = th[0]*gx + th[1]*gy + th[2];
  float sy = th[3]*gx + th[4]*gy + th[5];
  float px = (sx + 1.0f) * ((float)WW * 0.5f) - 0.5f;
  float py = (sy + 1.0f) * ((float)HH * 0.5f) - 0.5f;
  float x0 = floorf(px), y0 = floorf(py);
  float wx1 = px - x0, wx0 = 1.0f - wx1;
  float wy1 = py - y0, wy0 = 1.0f - wy1;
  const float* p0 = psm + (size_t)(n*2 + 0)*HW;
  const float* p1 = psm + (size_t)(n*2 + 1)*HW;
  float yy[2] = {y0, y0 + 1.0f};
  float xx[2] = {x0, x0 + 1.0f};
  float wgt[2][2] = {{wy0*wx0, wy0*wx1}, {wy1*wx0, wy1*wx1}};
  float out = 0.0f;
  for (int iy = 0; iy < 2; ++iy) {
    for (int ix = 0; ix < 2; ++ix) {
      float yv = yy[iy], xv = xx[ix];
      float yc = fminf(fmaxf(yv, 0.0f), (float)(HH-1));
      float xc = fminf(fmaxf(xv, 0.0f), (float)(WW-1));
      int yi = (int)yc, xi = (int)xc;
      int idx = yi*WW + xi;
      float m = fmaxf(p0[idx], p1[idx]);
      float v = 1.0f / (1.0f + expf(-m));
      bool valid = (yv >= 0.0f) && (yv <= (float)(HH-1)) && (xv >= 0.0f) && (xv <= (float)(WW-1));
      out += (valid ? v : 0.0f) * wgt[iy][ix];
    }
  }
  conf_w[(size_t)n*HW + h*WW + w] = out;
}

// --- Kernel 2: exact K-th largest per image via 4-round MSB radix select ---
// 8-replica LDS histogram (kills the ~64-way same-bucket atomic serialization
// on round 0 where sigmoid outputs concentrate in 2 exponent buckets), float4
// scan loads, wave-parallel descending-bin selection.
#define REP 8
__global__ __launch_bounds__(256) void topk_kernel(const float* __restrict__ conf_w,
                                                   float* __restrict__ tau) {
  __shared__ unsigned int hist[256*REP];
  __shared__ unsigned int s_prefix;
  __shared__ int s_k;
  int n = blockIdx.x;
  const float4* src = (const float4*)(conf_w + (size_t)n*HW);
  int rep = threadIdx.x & (REP-1);
  if (threadIdx.x == 0) { s_prefix = 0u; s_k = KTOP; }
  __syncthreads();
  for (int round = 0; round < 4; ++round) {
    int shift = 24 - round*8;
    for (int i = threadIdx.x; i < 256*REP; i += 256) hist[i] = 0u;
    __syncthreads();
    unsigned int prefix = s_prefix;
    unsigned int maskhi = (round == 0) ? 0u : (0xFFFFFFFFu << (shift + 8));
    for (int i = threadIdx.x; i < HW/4; i += 256) {
      float4 v = src[i];
      unsigned int u0 = __float_as_uint(v.x);
      unsigned int u1 = __float_as_uint(v.y);
      unsigned int u2 = __float_as_uint(v.z);
      unsigned int u3 = __float_as_uint(v.w);
      if ((u0 & maskhi) == prefix) atomicAdd(&hist[((u0 >> shift) & 255u)*REP + rep], 1u);
      if ((u1 & maskhi) == prefix) atomicAdd(&hist[((u1 >> shift) & 255u)*REP + rep], 1u);
      if ((u2 & maskhi) == prefix) atomicAdd(&hist[((u2 >> shift) & 255u)*REP + rep], 1u);
      if ((u3 & maskhi) == prefix) atomicAdd(&hist[((u3 >> shift) & 255u)*REP + rep], 1u);
    }
    __syncthreads();
    if (threadIdx.x < 64) {
      int lane = threadIdx.x;
      // lane covers 4 bins in DESCENDING order: bin = 255 - (lane*4 + t)
      unsigned int c[4];
      unsigned int local = 0u;
      for (int t = 0; t < 4; ++t) {
        int bin = 255 - (lane*4 + t);
        unsigned int s = 0u;
        for (int r = 0; r < REP; ++r) s += hist[bin*REP + r];
        c[t] = s; local += s;
      }
      unsigned int inc = local;
      for (int off = 1; off < 64; off <<= 1) {
        unsigned int o = __shfl_up(inc, off);
        if (lane >= off) inc += o;
      }
      unsigned int run = inc - local;   // exclusive prefix (count of strictly-higher bins)
      int k = s_k;
      for (int t = 0; t < 4; ++t) {
        if (run < (unsigned int)k && run + c[t] >= (unsigned int)k) {
          int bin = 255 - (lane*4 + t);
          s_prefix = prefix | ((unsigned int)bin << shift);
          s_k = k - (int)run;
        }
        run += c[t];
      }
    }
    __syncthreads();
  }
  if (threadIdx.x == 0) tau[n] = __uint_as_float(s_prefix);
}

// --- Kernel 3: weights fuse_w[k][c][dy][dx] -> wtp[(dy*7+dx)*64 + k][c] bf16 ---
__global__ void pack_w_kernel(const float* __restrict__ fw, __bf16* __restrict__ wtp) {
  int idx = blockIdx.x*256 + threadIdx.x;
  if (idx >= CCH*CCH*49) return;
  int c = idx & 63;
  int k = (idx >> 6) & 63;
  int dydx = idx >> 12;
  wtp[((size_t)dydx*CCH + k)*CCH + c] = (__bf16)fw[((size_t)k*CCH + c)*49 + dydx];
}

// --- Kernel 4: fused warp + mask + mean over L, write bf16 NHWC into padded buffer ---
__global__ __launch_bounds__(256) void warp_avg_kernel(
    const float* __restrict__ x, const float* __restrict__ ptm,
    const float* __restrict__ conf_w, const float* __restrict__ tau,
    __bf16* __restrict__ pad) {
  int tx = threadIdx.x;     // w within tile, 0..63
  int cq = threadIdx.y;     // channel quarter, 0..3
  int w = blockIdx.x*64 + tx;
  int h = blockIdx.y;
  int b = blockIdx.z;
  if (w >= WW) return;      // halo stays zero from memset
  float acc[16];
#pragma unroll
  for (int i = 0; i < 16; ++i) acc[i] = 0.0f;
  float gy = ((float)h + 0.5f) * (float)(2.0/100.0) - 1.0f;
  float gx = ((float)w + 0.5f) * (float)(2.0/352.0) - 1.0f;
  for (int l = 0; l < LL; ++l) {
    int n = b*LL + l;
    float mk = 1.0f;
    if (l != 0)
      mk = (conf_w[(size_t)n*HW + h*WW + w] >= tau[n]) ? 1.0f : 0.0f;
    if (mk == 0.0f) continue;   // skip 4*16 loads when masked out
    float th[6];
    load_theta(ptm, b, l, th);
    float sx = th[0]*gx + th[1]*gy + th[2];
    float sy = th[3]*gx + th[4]*gy + th[5];
    float px = (sx + 1.0f) * ((float)WW*0.5f) - 0.5f;
    float py = (sy + 1.0f) * ((float)HH*0.5f) - 0.5f;
    float x0 = floorf(px), y0 = floorf(py);
    float wx1 = px - x0, wx0 = 1.0f - wx1;
    float wy1 = py - y0, wy0 = 1.0f - wy1;
    float y1 = y0 + 1.0f, x1 = x0 + 1.0f;
    bool vy0 = (y0 >= 0.0f) && (y0 <= (float)(HH-1));
    bool vy1 = (y1 >= 0.0f) && (y1 <= (float)(HH-1));
    bool vx0 = (x0 >= 0.0f) && (x0 <= (float)(WW-1));
    bool vx1 = (x1 >= 0.0f) && (x1 <= (float)(WW-1));
    int yi0 = (int)fminf(fmaxf(y0, 0.0f), (float)(HH-1));
    int yi1 = (int)fminf(fmaxf(y1, 0.0f), (float)(HH-1));
    int xi0 = (int)fminf(fmaxf(x0, 0.0f), (float)(WW-1));
    int xi1 = (int)fminf(fmaxf(x1, 0.0f), (float)(WW-1));
    float w00 = wy0*wx0 * ((vy0 && vx0) ? 1.0f : 0.0f);
    float w01 = wy0*wx1 * ((vy0 && vx1) ? 1.0f : 0.0f);
    float w10 = wy1*wx0 * ((vy1 && vx0) ? 1.0f : 0.0f);
    float w11 = wy1*wx1 * ((vy1 && vx1) ? 1.0f : 0.0f);
    int o00 = yi0*WW + xi0, o01 = yi0*WW + xi1;
    int o10 = yi1*WW + xi0, o11 = yi1*WW + xi1;
    const float* xb = x + ((size_t)n*CCH + cq*16)*HW;
#pragma unroll
    for (int c = 0; c < 16; ++c) {
      const float* xc = xb + (size_t)c*HW;
      acc[c] += xc[o00]*w00 + xc[o01]*w01 + xc[o10]*w10 + xc[o11]*w11;
    }
  }
  __bf16* dst = pad + (((size_t)b*HP + (h+3))*WP + (w+3))*CCH + cq*16;
#pragma unroll
  for (int c = 0; c < 16; ++c) dst[c] = (__bf16)(acc[c]*0.2f);
}

// --- Kernel 5: 7x7 conv as implicit GEMM, bf16 MFMA 16x16x32 ---
// A = weights (M=kout), B = input pixels (N=w run), K = cin (2 chunks of 32) x 49 taps.
// dx and kc fully unrolled -> 14 independent {5 loads, 4 MFMA} bodies per dy row
// for deep VMEM pipelining; launch_bounds(256,4) caps VGPR at 128.
__global__ __launch_bounds__(256, 4) void conv_kernel(
    const __bf16* __restrict__ pad, const __bf16* __restrict__ wtp,
    const float* __restrict__ fb, float* __restrict__ out) {
  int tid = threadIdx.x;
  int wave = tid >> 6, lane = tid & 63;
  int quad = lane >> 4, l16 = lane & 15;
  int h = blockIdx.y, b = blockIdx.z;
  int wpix = blockIdx.x*64 + wave*16 + l16;
  f32x4 acc0 = {0.f,0.f,0.f,0.f}, acc1 = {0.f,0.f,0.f,0.f};
  f32x4 acc2 = {0.f,0.f,0.f,0.f}, acc3 = {0.f,0.f,0.f,0.f};
  const __bf16* prow = pad + (((size_t)b*HP + h)*WP + wpix)*CCH + quad*8;
#pragma unroll 1
  for (int dy = 0; dy < 7; ++dy) {
    const __bf16* pinrow = prow + dy*WP*CCH;
    const __bf16* pwrow  = wtp + ((size_t)dy*7*CCH + l16)*CCH + quad*8;
#pragma unroll
    for (int dx = 0; dx < 7; ++dx) {
      const __bf16* pin = pinrow + dx*CCH;
      const __bf16* pw  = pwrow + dx*CCH*CCH;
#pragma unroll
      for (int kc = 0; kc < 2; ++kc) {
        bf16x8 bf = *reinterpret_cast<const bf16x8*>(pin + kc*32);
        bf16x8 a0 = *reinterpret_cast<const bf16x8*>(pw + kc*32);
        bf16x8 a1 = *reinterpret_cast<const bf16x8*>(pw + 16*CCH + kc*32);
        bf16x8 a2 = *reinterpret_cast<const bf16x8*>(pw + 32*CCH + kc*32);
        bf16x8 a3 = *reinterpret_cast<const bf16x8*>(pw + 48*CCH + kc*32);
        acc0 = __builtin_amdgcn_mfma_f32_16x16x32_bf16(a0, bf, acc0, 0, 0, 0);
        acc1 = __builtin_amdgcn_mfma_f32_16x16x32_bf16(a1, bf, acc1, 0, 0, 0);
        acc2 = __builtin_amdgcn_mfma_f32_16x16x32_bf16(a2, bf, acc2, 0, 0, 0);
        acc3 = __builtin_amdgcn_mfma_f32_16x16x32_bf16(a3, bf, acc3, 0, 0, 0);
      }
    }
  }
  if (wpix < WW) {
    int base = (b*CCH*HH + h)*WW + wpix;
#pragma unroll
    for (int r = 0; r < 4; ++r) {
      int k0 = 0*16 + quad*4 + r;
      int k1 = 1*16 + quad*4 + r;
      int k2 = 2*16 + quad*4 + r;
      int k3 = 3*16 + quad*4 + r;
      out[base + k0*HW] = acc0[r] + fb[k0];
      out[base + k1*HW] = acc1[r] + fb[k1];
      out[base + k2*HW] = acc2[r] + fb[k2];
      out[base + k3*HW] = acc3[r] + fb[k3];
    }
  }
}

extern "C" void kernel_launch(void* const* d_in, const int* in_sizes, int n_in,
                              void* d_out, int out_size, void* d_ws, size_t ws_size,
                              hipStream_t stream) {
  (void)in_sizes; (void)n_in; (void)out_size; (void)ws_size;
  const float* x   = (const float*)d_in[0];
  const float* psm = (const float*)d_in[1];
  // d_in[2] = record_len (unused by reference)
  const float* ptm = (const float*)d_in[3];
  const float* fw  = (const float*)d_in[4];
  const float* fb  = (const float*)d_in[5];
  float* out = (float*)d_out;
  char* ws = (char*)d_ws;
  float*  conf = (float*)(ws + WS_CONF);
  float*  tau  = (float*)(ws + WS_TAU);
  __bf16* wtp  = (__bf16*)(ws + WS_WTP);
  __bf16* pad  = (__bf16*)(ws + WS_PAD);

  hipMemsetAsync(pad, 0, PAD_BYTES, stream);
  conf_warp_kernel<<<dim3(3, HH, NN), 128, 0, stream>>>(psm, ptm, conf);
  topk_kernel<<<NN, 256, 0, stream>>>(conf, tau);
  pack_w_kernel<<<(CCH*CCH*49 + 255)/256, 256, 0, stream>>>(fw, wtp);
  warp_avg_kernel<<<dim3(6, HH, NB), dim3(64, 4), 0, stream>>>(x, ptm, conf, tau, pad);
  conv_kernel<<<dim3(6, HH, NB), 256, 0, stream>>>(pad, wtp, fb, out);
}